// Round 6
// baseline (533.325 us; speedup 1.0000x reference)
//
#include <hip/hip_runtime.h>
#include <hip/hip_bf16.h>

typedef unsigned short u16;
typedef __attribute__((ext_vector_type(8))) short s16x8;
typedef __attribute__((ext_vector_type(4))) float f32x4;

#define GLOAD16(src, dst)                                                   \
  __builtin_amdgcn_global_load_lds(                                         \
      (const __attribute__((address_space(1))) void*)(src),                 \
      (__attribute__((address_space(3))) void*)(dst), 16, 0, 0)

__device__ inline u16 f2bf(float f) {
  unsigned u = __float_as_uint(f);
  unsigned r = u + 0x7FFFu + ((u >> 16) & 1u);
  return (u16)(r >> 16);
}
__device__ inline float bf2f(u16 h) { return __uint_as_float(((unsigned)h) << 16); }
__device__ inline void split_hl(float f, u16& hi, u16& lo) {
  hi = f2bf(f);
  lo = f2bf(f - bf2f(hi));
}

// Packed operand layout (GEMM A-side and producer-side), swizzle baked in:
// element (node, f) lives at:
//   (f>>5)*MpadS + node*32 + ((((f>>3)&3) ^ ((node>>1)&3))<<3) + (f&7)
// where MpadS = Mpad*32. K-tile read by a GEMM block = contiguous bytes.
__device__ inline size_t pk_idx(int node, int f, size_t MpadS) {
  return (size_t)(f >> 5) * MpadS + (size_t)node * 32 +
         (size_t)(((((f >> 3) & 3) ^ ((node >> 1) & 3)) << 3) + (f & 7));
}

// ---------------------------------------------------------------------------
// CSR build
// ---------------------------------------------------------------------------
__global__ void k_hist(const int* __restrict__ dst, int* __restrict__ deg, int nE) {
  int i = blockIdx.x * blockDim.x + threadIdx.x;
  if (i < nE) atomicAdd(&deg[dst[i]], 1);
}

__global__ void k_scan_chunks(const int* __restrict__ deg, int* __restrict__ excl,
                              int* __restrict__ partials, int n) {
  __shared__ int sd[256];
  const int t = threadIdx.x;
  const int base = blockIdx.x * 1024 + t * 4;
  int v0 = (base + 0 < n) ? deg[base + 0] : 0;
  int v1 = (base + 1 < n) ? deg[base + 1] : 0;
  int v2 = (base + 2 < n) ? deg[base + 2] : 0;
  int v3 = (base + 3 < n) ? deg[base + 3] : 0;
  sd[t] = v0 + v1 + v2 + v3;
  __syncthreads();
  for (int off = 1; off < 256; off <<= 1) {
    int x = 0;
    if (t >= off) x = sd[t - off];
    __syncthreads();
    sd[t] += x;
    __syncthreads();
  }
  int run = (t > 0) ? sd[t - 1] : 0;
  if (base + 0 < n) excl[base + 0] = run;
  run += v0;
  if (base + 1 < n) excl[base + 1] = run;
  run += v1;
  if (base + 2 < n) excl[base + 2] = run;
  run += v2;
  if (base + 3 < n) excl[base + 3] = run;
  if (t == 255) partials[blockIdx.x] = sd[255];
}

__global__ void k_scan_partials(int* __restrict__ partials, int nchunk) {
  const int t = threadIdx.x;
  int orig = (t < nchunk) ? partials[t] : 0;
  int v = orig;
  for (int off = 1; off < 64; off <<= 1) {
    int y = __shfl_up(v, off, 64);
    if (t >= off) v += y;
  }
  if (t < nchunk) partials[t] = v - orig;
}

__global__ void k_add_offsets(int* __restrict__ rowstart, const int* __restrict__ chunk_off,
                              int n, int nE) {
  int i = blockIdx.x * blockDim.x + threadIdx.x;
  if (i < n) rowstart[i] += chunk_off[i >> 10];
  if (i == n) rowstart[n] = nE;
}

__global__ void k_fill(const int* __restrict__ src, const int* __restrict__ dst,
                       const int* __restrict__ rowstart, int* __restrict__ cursor,
                       int* __restrict__ csr, int nE) {
  int i = blockIdx.x * blockDim.x + threadIdx.x;
  if (i < nE) {
    int d = dst[i];
    int p = rowstart[d] + atomicAdd(&cursor[d], 1);
    csr[p] = src[i];
  }
}

// ---------------------------------------------------------------------------
// fp32 -> packed bf16 hi/lo plane converters
// ---------------------------------------------------------------------------
__global__ void k_cvt(const float* __restrict__ X, u16* __restrict__ hi,
                      u16* __restrict__ lo, long n, size_t MpadS) {
  long i = (long)(blockIdx.x * blockDim.x + threadIdx.x) * 4;
  if (i >= n) return;
  float4 v = *(const float4*)&X[i];
  u16 h0, l0, h1, l1, h2, l2, h3, l3;
  split_hl(v.x, h0, l0);
  split_hl(v.y, h1, l1);
  split_hl(v.z, h2, l2);
  split_hl(v.w, h3, l3);
  int node = (int)(i >> 7), f = (int)(i & 127);
  size_t o = pk_idx(node, f, MpadS);
  *(ushort4*)&hi[o] = make_ushort4(h0, h1, h2, h3);
  *(ushort4*)&lo[o] = make_ushort4(l0, l1, l2, l3);
}

// W[K][256] -> packed-swizzled [kt][256 cols][32], col-plane stride 8192 shorts
__global__ void k_cvt_wt(const float* __restrict__ W, u16* __restrict__ thi,
                         u16* __restrict__ tlo, int K) {
  int i = blockIdx.x * blockDim.x + threadIdx.x;
  if (i >= K * 256) return;
  int k = i >> 8, n = i & 255;
  u16 h, l;
  split_hl(W[i], h, l);
  size_t o = (size_t)(k >> 5) * 8192 + (size_t)n * 32 +
             (size_t)(((((k >> 3) & 3) ^ ((n >> 1) & 3)) << 3) + (k & 7));
  thi[o] = h;
  tlo[o] = l;
}

// ---------------------------------------------------------------------------
// Mean aggregation (one wave per node); outputs packed hi/lo planes
// ---------------------------------------------------------------------------
__global__ void k_agg128_hl(const float* __restrict__ X, const int* __restrict__ rs,
                            const int* __restrict__ csr, u16* __restrict__ ohi,
                            u16* __restrict__ olo, int M, size_t MpadS) {
  int wid = (blockIdx.x * blockDim.x + threadIdx.x) >> 6;
  int lane = threadIdx.x & 63;
  if (wid >= M) return;
  int s0 = rs[wid], s1 = rs[wid + 1];
  float ax = 0.f, ay = 0.f;
  int e = s0;
  for (; e + 1 < s1; e += 2) {
    int sa = csr[e], sb = csr[e + 1];
    float2 va = *(const float2*)&X[(size_t)sa * 128 + lane * 2];
    float2 vb = *(const float2*)&X[(size_t)sb * 128 + lane * 2];
    ax += va.x + vb.x;
    ay += va.y + vb.y;
  }
  if (e < s1) {
    float2 va = *(const float2*)&X[(size_t)csr[e] * 128 + lane * 2];
    ax += va.x;
    ay += va.y;
  }
  float inv = 1.0f / fmaxf((float)(s1 - s0), 1.0f);
  ax *= inv;
  ay *= inv;
  u16 h0, l0, h1, l1;
  split_hl(ax, h0, l0);
  split_hl(ay, h1, l1);
  size_t o = pk_idx(wid, 2 * lane, MpadS);
  *(ushort2*)&ohi[o] = make_ushort2(h0, h1);
  *(ushort2*)&olo[o] = make_ushort2(l0, l1);
}

__global__ void k_agg256_hl(const u16* __restrict__ Xhi, const u16* __restrict__ Xlo,
                            const int* __restrict__ rs, const int* __restrict__ csr,
                            u16* __restrict__ ohi, u16* __restrict__ olo, int M,
                            size_t MpadS) {
  int wid = (blockIdx.x * blockDim.x + threadIdx.x) >> 6;
  int lane = threadIdx.x & 63;
  if (wid >= M) return;
  int s0 = rs[wid], s1 = rs[wid + 1];
  const size_t ktb = (size_t)(lane >> 3) * MpadS;
  const int cg = (lane >> 1) & 3;
  const int off = (lane & 1) * 4;
  float a0 = 0.f, a1 = 0.f, a2 = 0.f, a3 = 0.f;
  int e = s0;
  for (; e + 1 < s1; e += 2) {
    int na = csr[e], nb = csr[e + 1];
    size_t ba = ktb + (size_t)na * 32 + ((cg ^ ((na >> 1) & 3)) << 3) + off;
    size_t bb = ktb + (size_t)nb * 32 + ((cg ^ ((nb >> 1) & 3)) << 3) + off;
    ushort4 ha = *(const ushort4*)&Xhi[ba];
    ushort4 la = *(const ushort4*)&Xlo[ba];
    ushort4 hb = *(const ushort4*)&Xhi[bb];
    ushort4 lb = *(const ushort4*)&Xlo[bb];
    a0 += bf2f(ha.x) + bf2f(la.x) + bf2f(hb.x) + bf2f(lb.x);
    a1 += bf2f(ha.y) + bf2f(la.y) + bf2f(hb.y) + bf2f(lb.y);
    a2 += bf2f(ha.z) + bf2f(la.z) + bf2f(hb.z) + bf2f(lb.z);
    a3 += bf2f(ha.w) + bf2f(la.w) + bf2f(hb.w) + bf2f(lb.w);
  }
  if (e < s1) {
    int na = csr[e];
    size_t ba = ktb + (size_t)na * 32 + ((cg ^ ((na >> 1) & 3)) << 3) + off;
    ushort4 ha = *(const ushort4*)&Xhi[ba];
    ushort4 la = *(const ushort4*)&Xlo[ba];
    a0 += bf2f(ha.x) + bf2f(la.x);
    a1 += bf2f(ha.y) + bf2f(la.y);
    a2 += bf2f(ha.z) + bf2f(la.z);
    a3 += bf2f(ha.w) + bf2f(la.w);
  }
  float inv = 1.0f / fmaxf((float)(s1 - s0), 1.0f);
  a0 *= inv;
  a1 *= inv;
  a2 *= inv;
  a3 *= inv;
  u16 h0, l0, h1, l1, h2, l2, h3, l3;
  split_hl(a0, h0, l0);
  split_hl(a1, h1, l1);
  split_hl(a2, h2, l2);
  split_hl(a3, h3, l3);
  size_t o = ktb + (size_t)wid * 32 + ((cg ^ ((wid >> 1) & 3)) << 3) + off;
  *(ushort4*)&ohi[o] = make_ushort4(h0, h1, h2, h3);
  *(ushort4*)&olo[o] = make_ushort4(l0, l1, l2, l3);
}

// ---------------------------------------------------------------------------
// Dual bf16x3 MFMA GEMM on packed operands, counted-vmcnt pipeline:
// C[M][0:256] = relu(A1@W1 + A2@W2 + bias).  BM=64, BN=256 (full), BK=32.
// 4 waves; wave w owns cols w*64..+63; per-wave 48 MFMA/tile.
// Staging is PURELY LINEAR (layout pre-swizzled): 10 x GLOAD16/thread/tile,
// each wave-instr = 1 KB contiguous; tile = 4-16 KB contiguous runs -> full
// HBM burst efficiency. Frag ds_read_b128 hits 2-way banks (free).
// ---------------------------------------------------------------------------
template <int OUT_HL>
__global__ __launch_bounds__(256) void k_gemm_mfma(
    const u16* __restrict__ A1h, const u16* __restrict__ A1l,
    const u16* __restrict__ A2h, const u16* __restrict__ A2l,
    const u16* __restrict__ W1h, const u16* __restrict__ W1l,
    const u16* __restrict__ W2h, const u16* __restrict__ W2l,
    const float* __restrict__ bias, u16* __restrict__ Ohi, u16* __restrict__ Olo,
    float* __restrict__ Of32, int M, int K, size_t MpadS) {
  // A: [64 rows][32 shorts] = 4 KB/plane; B: [256 cols][32 shorts] = 16 KB/plane
  __shared__ short sAh[2][2048], sAl[2][2048], sBh[2][8192], sBl[2][8192];
  const int t = threadIdx.x;
  const int l = t & 63;
  const int w = t >> 6;
  const int bm0 = blockIdx.x * 64;
  const int KT = K >> 5;
  const int NT = 2 * KT;

  f32x4 acc[4][4];
#pragma unroll
  for (int m = 0; m < 4; m++)
#pragma unroll
    for (int n = 0; n < 4; n++) acc[m][n] = (f32x4){0.f, 0.f, 0.f, 0.f};

#define STAGE(buf, it)                                                        \
  do {                                                                        \
    int ph_ = (it) >= KT;                                                     \
    int kt_ = (it) - (ph_ ? KT : 0);                                          \
    const u16* Ah_ = ph_ ? A2h : A1h;                                         \
    const u16* Al_ = ph_ ? A2l : A1l;                                         \
    const u16* Bh_ = ph_ ? W2h : W1h;                                         \
    const u16* Bl_ = ph_ ? W2l : W1l;                                         \
    size_t ab_ = (size_t)kt_ * MpadS + (size_t)bm0 * 32 + t * 8;              \
    size_t bb_ = (size_t)kt_ * 8192 + t * 8;                                  \
    GLOAD16(Ah_ + ab_, &sAh[buf][t * 8]);                                     \
    GLOAD16(Al_ + ab_, &sAl[buf][t * 8]);                                     \
    GLOAD16(Bh_ + bb_ + 0 * 2048, &sBh[buf][t * 8 + 0 * 2048]);               \
    GLOAD16(Bh_ + bb_ + 1 * 2048, &sBh[buf][t * 8 + 1 * 2048]);               \
    GLOAD16(Bh_ + bb_ + 2 * 2048, &sBh[buf][t * 8 + 2 * 2048]);               \
    GLOAD16(Bh_ + bb_ + 3 * 2048, &sBh[buf][t * 8 + 3 * 2048]);               \
    GLOAD16(Bl_ + bb_ + 0 * 2048, &sBl[buf][t * 8 + 0 * 2048]);               \
    GLOAD16(Bl_ + bb_ + 1 * 2048, &sBl[buf][t * 8 + 1 * 2048]);               \
    GLOAD16(Bl_ + bb_ + 2 * 2048, &sBl[buf][t * 8 + 2 * 2048]);               \
    GLOAD16(Bl_ + bb_ + 3 * 2048, &sBl[buf][t * 8 + 3 * 2048]);               \
  } while (0)

  STAGE(0, 0);
  STAGE(1, 1);

  const int lr = l & 15;
  const int cw = l >> 4;
  const int csx = ((cw ^ ((lr >> 1) & 3)) << 3);  // swizzled chunk, short units

  for (int it = 0; it < NT; ++it) {
    const int buf = it & 1;
    // tile-it's 10 loads landed (tile-it+1's 10 may stay in flight)
    if (it + 1 < NT) {
      asm volatile("s_waitcnt vmcnt(10)" ::: "memory");
    } else {
      asm volatile("s_waitcnt vmcnt(0)" ::: "memory");
    }
    __builtin_amdgcn_s_barrier();

    s16x8 ah[4], al[4], bh[4], bl[4];
#pragma unroll
    for (int m = 0; m < 4; ++m) {
      int ao = (m * 16 + lr) * 32 + csx;
      ah[m] = *(const s16x8*)&sAh[buf][ao];
      al[m] = *(const s16x8*)&sAl[buf][ao];
    }
#pragma unroll
    for (int n = 0; n < 4; ++n) {
      int bo = (w * 64 + n * 16 + lr) * 32 + csx;
      bh[n] = *(const s16x8*)&sBh[buf][bo];
      bl[n] = *(const s16x8*)&sBl[buf][bo];
    }
    asm volatile("s_waitcnt lgkmcnt(0)" ::: "memory");  // my reads done
    __builtin_amdgcn_sched_barrier(0);                  // rule #18 fence
    __builtin_amdgcn_s_barrier();                       // everyone's reads done
    if (it + 2 < NT) STAGE(buf, it + 2);                // safe overwrite, in flight

#pragma unroll
    for (int n = 0; n < 4; ++n) {
#pragma unroll
      for (int m = 0; m < 4; ++m) {
        acc[m][n] = __builtin_amdgcn_mfma_f32_16x16x32_bf16(ah[m], bh[n], acc[m][n], 0, 0, 0);
        acc[m][n] = __builtin_amdgcn_mfma_f32_16x16x32_bf16(al[m], bh[n], acc[m][n], 0, 0, 0);
        acc[m][n] = __builtin_amdgcn_mfma_f32_16x16x32_bf16(ah[m], bl[n], acc[m][n], 0, 0, 0);
      }
    }
  }
#undef STAGE

  // epilogue: D col = lane&15 (+16n+64w), row = (lane>>4)*4 + j (+16m)
  const int colb = w * 64 + lr;
  const int rwb = bm0 + (l >> 4) * 4;
#pragma unroll
  for (int n = 0; n < 4; ++n) {
    int col = colb + n * 16;
    float bc = bias[col];
#pragma unroll
    for (int m = 0; m < 4; ++m) {
#pragma unroll
      for (int j = 0; j < 4; ++j) {
        int r = rwb + m * 16 + j;
        if (r < M) {
          float v = fmaxf(acc[m][n][j] + bc, 0.f);
          if (OUT_HL) {
            u16 h, lo2;
            split_hl(v, h, lo2);
            size_t o = pk_idx(r, col, MpadS);
            Ohi[o] = h;
            Olo[o] = lo2;
          } else {
            Of32[(size_t)r * 256 + col] = v;
          }
        }
      }
    }
  }
}

// ---------------------------------------------------------------------------
// Classifier: out[M][16] = h2[M][256] @ wc[256][16] + bc
// ---------------------------------------------------------------------------
__global__ void k_classifier(const float* __restrict__ h2, const float* __restrict__ wc,
                             const float* __restrict__ bc, float* __restrict__ outv, int M) {
  __shared__ float wcs[4096];
  __shared__ float bcs[16];
  const int t = threadIdx.x;
  for (int i = t; i < 4096; i += 256) wcs[i] = wc[i];
  if (t < 16) bcs[t] = bc[t];
  __syncthreads();
  int row = blockIdx.x * 16 + (t >> 4);
  int cls = t & 15;
  if (row >= M) return;
  const float* hr = h2 + (size_t)row * 256;
  float acc = 0.f;
  for (int k = 0; k < 256; k += 4) {
    float4 h = *(const float4*)&hr[k];
    acc += h.x * wcs[(k + 0) * 16 + cls];
    acc += h.y * wcs[(k + 1) * 16 + cls];
    acc += h.z * wcs[(k + 2) * 16 + cls];
    acc += h.w * wcs[(k + 3) * 16 + cls];
  }
  outv[(size_t)row * 16 + cls] = acc + bcs[cls];
}

// ---------------------------------------------------------------------------
extern "C" void kernel_launch(void* const* d_in, const int* in_sizes, int n_in,
                              void* d_out, int out_size, void* d_ws, size_t ws_size,
                              hipStream_t stream) {
  const float* x = (const float*)d_in[0];
  const int* ei = (const int*)d_in[1];
  const float* w1l = (const float*)d_in[2];
  const float* b1l = (const float*)d_in[3];
  const float* w1r = (const float*)d_in[4];
  const float* w2l = (const float*)d_in[5];
  const float* b2l = (const float*)d_in[6];
  const float* w2r = (const float*)d_in[7];
  const float* wc = (const float*)d_in[8];
  const float* bc = (const float*)d_in[9];
  float* outp = (float*)d_out;

  const int nE = in_sizes[1] / 2;      // 600000
  const int M = in_sizes[0] / 128;     // 50000
  const int Mpad = (M + 63) & ~63;     // 50048
  const size_t MpadS = (size_t)Mpad * 32;
  const int* src = ei;
  const int* dst = ei + nE;

  char* ws = (char*)d_ws;
  const size_t SZ_P128 = (size_t)Mpad * 128 * 2;
  const size_t SZ_P256 = (size_t)Mpad * 256 * 2;

  int* deg = (int*)(ws + 0);
  int* cursor = (int*)(ws + 262144);
  int* rowstart = (int*)(ws + 524288);
  int* partials = (int*)(ws + 786432);
  int* csr = (int*)(ws + 1048576);
  u16* wt1l_h = (u16*)(ws + 3670016);
  u16* wt1l_l = (u16*)(ws + 3735552);
  u16* wt1r_h = (u16*)(ws + 3801088);
  u16* wt1r_l = (u16*)(ws + 3866624);
  u16* wt2l_h = (u16*)(ws + 3932160);
  u16* wt2l_l = (u16*)(ws + 4063232);
  u16* wt2r_h = (u16*)(ws + 4194304);
  u16* wt2r_l = (u16*)(ws + 4325376);
  char* big = ws + 4718592;
  u16* x_hi = (u16*)(big);
  u16* x_lo = (u16*)(big + SZ_P128);
  u16* n1_hi = (u16*)(big + 2 * SZ_P128);
  u16* n1_lo = (u16*)(big + 3 * SZ_P128);
  float* h2 = (float*)(big);  // overlays x/n1 planes (disjoint lifetime)
  char* big2 = big + 4 * SZ_P128;
  u16* h1_hi = (u16*)(big2);
  u16* h1_lo = (u16*)(big2 + SZ_P256);
  u16* n2_hi = (u16*)(big2 + 2 * SZ_P256);
  u16* n2_lo = (u16*)(big2 + 3 * SZ_P256);

  hipMemsetAsync(deg, 0, (size_t)M * sizeof(int), stream);
  hipMemsetAsync(cursor, 0, (size_t)M * sizeof(int), stream);

  const int eb = (nE + 255) / 256;
  k_hist<<<eb, 256, 0, stream>>>(dst, deg, nE);
  const int nchunk = (M + 1023) / 1024;
  k_scan_chunks<<<nchunk, 256, 0, stream>>>(deg, rowstart, partials, M);
  k_scan_partials<<<1, 64, 0, stream>>>(partials, nchunk);
  k_add_offsets<<<(M + 1 + 255) / 256, 256, 0, stream>>>(rowstart, partials, M, nE);
  k_fill<<<eb, 256, 0, stream>>>(src, dst, rowstart, cursor, csr, nE);

  // converts (packed+swizzled layouts)
  long nx = (long)M * 128;
  k_cvt<<<(int)((nx / 4 + 255) / 256), 256, 0, stream>>>(x, x_hi, x_lo, nx, MpadS);
  k_cvt_wt<<<(128 * 256 + 255) / 256, 256, 0, stream>>>(w1l, wt1l_h, wt1l_l, 128);
  k_cvt_wt<<<(128 * 256 + 255) / 256, 256, 0, stream>>>(w1r, wt1r_h, wt1r_l, 128);
  k_cvt_wt<<<(256 * 256 + 255) / 256, 256, 0, stream>>>(w2l, wt2l_h, wt2l_l, 256);
  k_cvt_wt<<<(256 * 256 + 255) / 256, 256, 0, stream>>>(w2r, wt2r_h, wt2r_l, 256);

  const int ggrid = Mpad / 64;

  // Layer 1
  k_agg128_hl<<<(M * 64 + 255) / 256, 256, 0, stream>>>(x, rowstart, csr, n1_hi, n1_lo, M,
                                                        MpadS);
  k_gemm_mfma<1><<<ggrid, 256, 0, stream>>>(n1_hi, n1_lo, x_hi, x_lo, wt1l_h, wt1l_l,
                                            wt1r_h, wt1r_l, b1l, h1_hi, h1_lo, nullptr,
                                            M, 128, MpadS);
  // Layer 2
  k_agg256_hl<<<(M * 64 + 255) / 256, 256, 0, stream>>>(h1_hi, h1_lo, rowstart, csr, n2_hi,
                                                        n2_lo, M, MpadS);
  k_gemm_mfma<0><<<ggrid, 256, 0, stream>>>(n2_hi, n2_lo, h1_hi, h1_lo, wt2l_h, wt2l_l,
                                            wt2r_h, wt2r_l, b2l, nullptr, nullptr, h2,
                                            M, 256, MpadS);
  // Classifier
  k_classifier<<<(M + 15) / 16, 256, 0, stream>>>(h2, wc, bc, outp, M);
}

// Round 7
// 442.015 us; speedup vs baseline: 1.2066x; 1.2066x over previous
//
#include <hip/hip_runtime.h>
#include <hip/hip_bf16.h>

typedef unsigned short u16;
typedef __attribute__((ext_vector_type(8))) short s16x8;
typedef __attribute__((ext_vector_type(8))) unsigned short u16x8;
typedef __attribute__((ext_vector_type(4))) float f32x4;

#define GLOAD16(src, dst)                                                   \
  __builtin_amdgcn_global_load_lds(                                         \
      (const __attribute__((address_space(1))) void*)(src),                 \
      (__attribute__((address_space(3))) void*)(dst), 16, 0, 0)

__device__ inline u16 f2bf(float f) {
  unsigned u = __float_as_uint(f);
  unsigned r = u + 0x7FFFu + ((u >> 16) & 1u);
  return (u16)(r >> 16);
}
__device__ inline float bf2f(u16 h) { return __uint_as_float(((unsigned)h) << 16); }
__device__ inline void split_hl(float f, u16& hi, u16& lo) {
  hi = f2bf(f);
  lo = f2bf(f - bf2f(hi));
}

// ---------------------------------------------------------------------------
// Fused node-feature layout (all GEMM A-side operands):
// row = KT segments of 128B; segment kt = 8 chunks of 16B, content chunk c
// (c<4: hi of dims kt*32+c*8..+7; c>=4: lo of dims kt*32+(c-4)*8..+7) stored
// at position c ^ (node&7).  Row stride = K*2 shorts.  Gather reads a node
// row as ONE contiguous run; GEMM stages it linearly into an identical LDS
// image (swizzle cancels: content at pos p for node n is p ^ (n&7)).
// ---------------------------------------------------------------------------

// ---------------------------------------------------------------------------
// CSR build
// ---------------------------------------------------------------------------
__global__ void k_hist(const int* __restrict__ dst, int* __restrict__ deg, int nE) {
  int i = blockIdx.x * blockDim.x + threadIdx.x;
  if (i < nE) atomicAdd(&deg[dst[i]], 1);
}

__global__ void k_scan_chunks(const int* __restrict__ deg, int* __restrict__ excl,
                              int* __restrict__ partials, int n) {
  __shared__ int sd[256];
  const int t = threadIdx.x;
  const int base = blockIdx.x * 1024 + t * 4;
  int v0 = (base + 0 < n) ? deg[base + 0] : 0;
  int v1 = (base + 1 < n) ? deg[base + 1] : 0;
  int v2 = (base + 2 < n) ? deg[base + 2] : 0;
  int v3 = (base + 3 < n) ? deg[base + 3] : 0;
  sd[t] = v0 + v1 + v2 + v3;
  __syncthreads();
  for (int off = 1; off < 256; off <<= 1) {
    int x = 0;
    if (t >= off) x = sd[t - off];
    __syncthreads();
    sd[t] += x;
    __syncthreads();
  }
  int run = (t > 0) ? sd[t - 1] : 0;
  if (base + 0 < n) excl[base + 0] = run;
  run += v0;
  if (base + 1 < n) excl[base + 1] = run;
  run += v1;
  if (base + 2 < n) excl[base + 2] = run;
  run += v2;
  if (base + 3 < n) excl[base + 3] = run;
  if (t == 255) partials[blockIdx.x] = sd[255];
}

__global__ void k_scan_partials(int* __restrict__ partials, int nchunk) {
  const int t = threadIdx.x;
  int orig = (t < nchunk) ? partials[t] : 0;
  int v = orig;
  for (int off = 1; off < 64; off <<= 1) {
    int y = __shfl_up(v, off, 64);
    if (t >= off) v += y;
  }
  if (t < nchunk) partials[t] = v - orig;
}

__global__ void k_add_offsets(int* __restrict__ rowstart, const int* __restrict__ chunk_off,
                              int n, int nE) {
  int i = blockIdx.x * blockDim.x + threadIdx.x;
  if (i < n) rowstart[i] += chunk_off[i >> 10];
  if (i == n) rowstart[n] = nE;
}

__global__ void k_fill(const int* __restrict__ src, const int* __restrict__ dst,
                       const int* __restrict__ rowstart, int* __restrict__ cursor,
                       int* __restrict__ csr, int nE) {
  int i = blockIdx.x * blockDim.x + threadIdx.x;
  if (i < nE) {
    int d = dst[i];
    int p = rowstart[d] + atomicAdd(&cursor[d], 1);
    csr[p] = src[i];
  }
}

// ---------------------------------------------------------------------------
// x fp32 -> fused layout (K=128: row = 256 shorts)
// ---------------------------------------------------------------------------
__global__ void k_cvt(const float* __restrict__ X, u16* __restrict__ Xf, long n) {
  long i = (long)(blockIdx.x * blockDim.x + threadIdx.x) * 4;
  if (i >= n) return;
  float4 v = *(const float4*)&X[i];
  u16 h[4], lo[4];
  split_hl(v.x, h[0], lo[0]);
  split_hl(v.y, h[1], lo[1]);
  split_hl(v.z, h[2], lo[2]);
  split_hl(v.w, h[3], lo[3]);
  int node = (int)(i >> 7), f = (int)(i & 127);
  int kt = f >> 5, c = (f >> 3) & 3, off = f & 7;
  size_t base = (size_t)node * 256 + kt * 64;
  size_t ohi = base + ((c ^ (node & 7)) * 8) + off;
  size_t olo = base + (((4 + c) ^ (node & 7)) * 8) + off;
  *(ushort4*)&Xf[ohi] = make_ushort4(h[0], h[1], h[2], h[3]);
  *(ushort4*)&Xf[olo] = make_ushort4(lo[0], lo[1], lo[2], lo[3]);
}

// W[K][256] -> packed-swizzled [kt][256 cols][32], col-plane stride 8192 shorts
__global__ void k_cvt_wt(const float* __restrict__ W, u16* __restrict__ thi,
                         u16* __restrict__ tlo, int K) {
  int i = blockIdx.x * blockDim.x + threadIdx.x;
  if (i >= K * 256) return;
  int k = i >> 8, n = i & 255;
  u16 h, l;
  split_hl(W[i], h, l);
  size_t o = (size_t)(k >> 5) * 8192 + (size_t)n * 32 +
             (size_t)(((((k >> 3) & 3) ^ ((n >> 1) & 3)) << 3) + (k & 7));
  thi[o] = h;
  tlo[o] = l;
}

// ---------------------------------------------------------------------------
// Layer-1 aggregation: gather fp32 x rows (contiguous), write fused n1
// ---------------------------------------------------------------------------
__global__ void k_agg128_hl(const float* __restrict__ X, const int* __restrict__ rs,
                            const int* __restrict__ csr, u16* __restrict__ Of, int M) {
  int wid = (blockIdx.x * blockDim.x + threadIdx.x) >> 6;
  int lane = threadIdx.x & 63;
  if (wid >= M) return;
  int s0 = rs[wid], s1 = rs[wid + 1];
  float ax = 0.f, ay = 0.f;
  int e = s0;
  for (; e + 1 < s1; e += 2) {
    int sa = csr[e], sb = csr[e + 1];
    float2 va = *(const float2*)&X[(size_t)sa * 128 + lane * 2];
    float2 vb = *(const float2*)&X[(size_t)sb * 128 + lane * 2];
    ax += va.x + vb.x;
    ay += va.y + vb.y;
  }
  if (e < s1) {
    float2 va = *(const float2*)&X[(size_t)csr[e] * 128 + lane * 2];
    ax += va.x;
    ay += va.y;
  }
  float inv = 1.0f / fmaxf((float)(s1 - s0), 1.0f);
  ax *= inv;
  ay *= inv;
  u16 h0, l0, h1, l1;
  split_hl(ax, h0, l0);
  split_hl(ay, h1, l1);
  // dims 2*lane, 2*lane+1
  int kt = lane >> 4, c = (lane >> 2) & 3, off = (2 * lane) & 7;
  size_t base = (size_t)wid * 256 + kt * 64;
  *(ushort2*)&Of[base + ((c ^ (wid & 7)) * 8) + off] = make_ushort2(h0, h1);
  *(ushort2*)&Of[base + (((4 + c) ^ (wid & 7)) * 8) + off] = make_ushort2(l0, l1);
}

// ---------------------------------------------------------------------------
// Layer-2 aggregation: gather fused h1 rows (1024B contiguous per edge),
// write fused n2.  Lane l owns content chunk c=l&7 of segment kt=l>>3.
// ---------------------------------------------------------------------------
__global__ void k_agg256_hl(const u16* __restrict__ Xf, const int* __restrict__ rs,
                            const int* __restrict__ csr, u16* __restrict__ Of, int M) {
  int wid = (blockIdx.x * blockDim.x + threadIdx.x) >> 6;
  int lane = threadIdx.x & 63;
  if (wid >= M) return;
  int s0 = rs[wid], s1 = rs[wid + 1];
  const int kt = lane >> 3, lc = lane & 7;
  float acc[8];
#pragma unroll
  for (int j = 0; j < 8; ++j) acc[j] = 0.f;
  int e = s0;
  for (; e + 1 < s1; e += 2) {
    int na = csr[e], nb = csr[e + 1];
    size_t ba = (size_t)na * 512 + kt * 64 + ((lc ^ (na & 7)) * 8);
    size_t bb = (size_t)nb * 512 + kt * 64 + ((lc ^ (nb & 7)) * 8);
    u16x8 va = *(const u16x8*)&Xf[ba];
    u16x8 vb = *(const u16x8*)&Xf[bb];
#pragma unroll
    for (int j = 0; j < 8; ++j) acc[j] += bf2f(va[j]) + bf2f(vb[j]);
  }
  if (e < s1) {
    int na = csr[e];
    size_t ba = (size_t)na * 512 + kt * 64 + ((lc ^ (na & 7)) * 8);
    u16x8 va = *(const u16x8*)&Xf[ba];
#pragma unroll
    for (int j = 0; j < 8; ++j) acc[j] += bf2f(va[j]);
  }
  float inv = 1.0f / fmaxf((float)(s1 - s0), 1.0f);
  // combine hi-part sums with lo-part sums (partner lane l^4, same dims)
  u16x8 ov;
  const bool isHi = lc < 4;
#pragma unroll
  for (int j = 0; j < 8; ++j) {
    float tot = (acc[j] + __shfl_xor(acc[j], 4)) * inv;
    u16 h, lo2;
    split_hl(tot, h, lo2);
    ov[j] = isHi ? h : lo2;
  }
  size_t o = (size_t)wid * 512 + kt * 64 + ((lc ^ (wid & 7)) * 8);
  *(u16x8*)&Of[o] = ov;
}

// ---------------------------------------------------------------------------
// Dual bf16x3 MFMA GEMM, counted-vmcnt pipeline, fused-A operands:
// C[M][0:256] = relu(A1@W1 + A2@W2 + bias).  BM=64, BN=256, BK=32.
// A tile = 64 nodes x 128B fused rows, staged LINEARLY (2 GLOAD16/thread);
// B packed per round 6 (8 GLOAD16/thread). vmcnt(10) steady state.
// ---------------------------------------------------------------------------
template <int OUT_HL>
__global__ __launch_bounds__(256) void k_gemm_mfma(
    const u16* __restrict__ A1, const u16* __restrict__ A2,
    const u16* __restrict__ W1h, const u16* __restrict__ W1l,
    const u16* __restrict__ W2h, const u16* __restrict__ W2l,
    const float* __restrict__ bias, u16* __restrict__ Ofu,
    float* __restrict__ Of32, int M, int K) {
  // A: [64 nodes][64 shorts] = 8 KB/buf; B: [256 cols][32 shorts] = 16 KB/plane/buf
  __shared__ short sA[2][4096], sBh[2][8192], sBl[2][8192];
  const int t = threadIdx.x;
  const int l = t & 63;
  const int w = t >> 6;
  const int bm0 = blockIdx.x * 64;
  const int KT = K >> 5;
  const int NT = 2 * KT;
  const int rowS = K * 2;  // shorts per fused row

  f32x4 acc[4][4];
#pragma unroll
  for (int m = 0; m < 4; m++)
#pragma unroll
    for (int n = 0; n < 4; n++) acc[m][n] = (f32x4){0.f, 0.f, 0.f, 0.f};

#define STAGE(buf, it)                                                        \
  do {                                                                        \
    int ph_ = (it) >= KT;                                                     \
    int kt_ = (it) - (ph_ ? KT : 0);                                          \
    const u16* A_ = ph_ ? A2 : A1;                                            \
    const u16* Bh_ = ph_ ? W2h : W1h;                                         \
    const u16* Bl_ = ph_ ? W2l : W1l;                                         \
    size_t a0_ = (size_t)(bm0 + (t >> 3)) * rowS + kt_ * 64 + (t & 7) * 8;    \
    size_t a1_ = (size_t)(bm0 + 32 + (t >> 3)) * rowS + kt_ * 64 + (t & 7) * 8; \
    GLOAD16(A_ + a0_, &sA[buf][t * 8]);                                       \
    GLOAD16(A_ + a1_, &sA[buf][2048 + t * 8]);                                \
    size_t bb_ = (size_t)kt_ * 8192 + t * 8;                                  \
    GLOAD16(Bh_ + bb_ + 0 * 2048, &sBh[buf][t * 8 + 0 * 2048]);               \
    GLOAD16(Bh_ + bb_ + 1 * 2048, &sBh[buf][t * 8 + 1 * 2048]);               \
    GLOAD16(Bh_ + bb_ + 2 * 2048, &sBh[buf][t * 8 + 2 * 2048]);               \
    GLOAD16(Bh_ + bb_ + 3 * 2048, &sBh[buf][t * 8 + 3 * 2048]);               \
    GLOAD16(Bl_ + bb_ + 0 * 2048, &sBl[buf][t * 8 + 0 * 2048]);               \
    GLOAD16(Bl_ + bb_ + 1 * 2048, &sBl[buf][t * 8 + 1 * 2048]);               \
    GLOAD16(Bl_ + bb_ + 2 * 2048, &sBl[buf][t * 8 + 2 * 2048]);               \
    GLOAD16(Bl_ + bb_ + 3 * 2048, &sBl[buf][t * 8 + 3 * 2048]);               \
  } while (0)

  STAGE(0, 0);
  STAGE(1, 1);

  const int lr = l & 15;
  const int cw = l >> 4;
  const int pa_hi = (cw ^ (lr & 7)) * 8;        // hi chunk position (shorts)
  const int pa_lo = ((4 + cw) ^ (lr & 7)) * 8;  // lo chunk position
  const int csx = (cw ^ ((lr >> 1) & 3)) * 8;   // B chunk position

  for (int it = 0; it < NT; ++it) {
    const int buf = it & 1;
    if (it + 1 < NT) {
      asm volatile("s_waitcnt vmcnt(10)" ::: "memory");
    } else {
      asm volatile("s_waitcnt vmcnt(0)" ::: "memory");
    }
    __builtin_amdgcn_s_barrier();

    s16x8 ah[4], al[4], bh[4], bl[4];
#pragma unroll
    for (int m = 0; m < 4; ++m) {
      int abase = (m * 16 + lr) * 64;
      ah[m] = *(const s16x8*)&sA[buf][abase + pa_hi];
      al[m] = *(const s16x8*)&sA[buf][abase + pa_lo];
    }
#pragma unroll
    for (int n = 0; n < 4; ++n) {
      int bo = (w * 64 + n * 16 + lr) * 32 + csx;
      bh[n] = *(const s16x8*)&sBh[buf][bo];
      bl[n] = *(const s16x8*)&sBl[buf][bo];
    }
    asm volatile("s_waitcnt lgkmcnt(0)" ::: "memory");
    __builtin_amdgcn_sched_barrier(0);
    __builtin_amdgcn_s_barrier();
    if (it + 2 < NT) STAGE(buf, it + 2);

#pragma unroll
    for (int n = 0; n < 4; ++n) {
#pragma unroll
      for (int m = 0; m < 4; ++m) {
        acc[m][n] = __builtin_amdgcn_mfma_f32_16x16x32_bf16(ah[m], bh[n], acc[m][n], 0, 0, 0);
        acc[m][n] = __builtin_amdgcn_mfma_f32_16x16x32_bf16(al[m], bh[n], acc[m][n], 0, 0, 0);
        acc[m][n] = __builtin_amdgcn_mfma_f32_16x16x32_bf16(ah[m], bl[n], acc[m][n], 0, 0, 0);
      }
    }
  }
#undef STAGE

  // epilogue: D col = lane&15 (+16n+64w), row = (lane>>4)*4 + j (+16m)
  const int colb = w * 64 + lr;
  const int rwb = bm0 + (l >> 4) * 4;
#pragma unroll
  for (int n = 0; n < 4; ++n) {
    int col = colb + n * 16;
    float bc = bias[col];
    int ckt = col >> 5, cc = (col >> 3) & 3, coff = col & 7;
#pragma unroll
    for (int m = 0; m < 4; ++m) {
#pragma unroll
      for (int j = 0; j < 4; ++j) {
        int r = rwb + m * 16 + j;
        if (r < M) {
          float v = fmaxf(acc[m][n][j] + bc, 0.f);
          if (OUT_HL) {
            u16 h, lo2;
            split_hl(v, h, lo2);
            size_t base = (size_t)r * 512 + ckt * 64;
            Ofu[base + ((cc ^ (r & 7)) * 8) + coff] = h;
            Ofu[base + (((4 + cc) ^ (r & 7)) * 8) + coff] = lo2;
          } else {
            Of32[(size_t)r * 256 + col] = v;
          }
        }
      }
    }
  }
}

// ---------------------------------------------------------------------------
// Classifier: out[M][16] = h2[M][256] @ wc[256][16] + bc
// ---------------------------------------------------------------------------
__global__ void k_classifier(const float* __restrict__ h2, const float* __restrict__ wc,
                             const float* __restrict__ bc, float* __restrict__ outv, int M) {
  __shared__ float wcs[4096];
  __shared__ float bcs[16];
  const int t = threadIdx.x;
  for (int i = t; i < 4096; i += 256) wcs[i] = wc[i];
  if (t < 16) bcs[t] = bc[t];
  __syncthreads();
  int row = blockIdx.x * 16 + (t >> 4);
  int cls = t & 15;
  if (row >= M) return;
  const float* hr = h2 + (size_t)row * 256;
  float acc = 0.f;
  for (int k = 0; k < 256; k += 4) {
    float4 h = *(const float4*)&hr[k];
    acc += h.x * wcs[(k + 0) * 16 + cls];
    acc += h.y * wcs[(k + 1) * 16 + cls];
    acc += h.z * wcs[(k + 2) * 16 + cls];
    acc += h.w * wcs[(k + 3) * 16 + cls];
  }
  outv[(size_t)row * 16 + cls] = acc + bcs[cls];
}

// ---------------------------------------------------------------------------
extern "C" void kernel_launch(void* const* d_in, const int* in_sizes, int n_in,
                              void* d_out, int out_size, void* d_ws, size_t ws_size,
                              hipStream_t stream) {
  const float* x = (const float*)d_in[0];
  const int* ei = (const int*)d_in[1];
  const float* w1l = (const float*)d_in[2];
  const float* b1l = (const float*)d_in[3];
  const float* w1r = (const float*)d_in[4];
  const float* w2l = (const float*)d_in[5];
  const float* b2l = (const float*)d_in[6];
  const float* w2r = (const float*)d_in[7];
  const float* wc = (const float*)d_in[8];
  const float* bc = (const float*)d_in[9];
  float* outp = (float*)d_out;

  const int nE = in_sizes[1] / 2;      // 600000
  const int M = in_sizes[0] / 128;     // 50000
  const int Mpad = (M + 63) & ~63;     // 50048
  const int* src = ei;
  const int* dst = ei + nE;

  char* ws = (char*)d_ws;
  const size_t SZ_F128 = (size_t)Mpad * 256 * 2;  // fused K=128 rows: 25,624,576 B
  const size_t SZ_F256 = (size_t)Mpad * 512 * 2;  // fused K=256 rows: 51,249,152 B

  int* deg = (int*)(ws + 0);
  int* cursor = (int*)(ws + 262144);
  int* rowstart = (int*)(ws + 524288);
  int* partials = (int*)(ws + 786432);
  int* csr = (int*)(ws + 1048576);
  u16* wt1l_h = (u16*)(ws + 3670016);
  u16* wt1l_l = (u16*)(ws + 3735552);
  u16* wt1r_h = (u16*)(ws + 3801088);
  u16* wt1r_l = (u16*)(ws + 3866624);
  u16* wt2l_h = (u16*)(ws + 3932160);
  u16* wt2l_l = (u16*)(ws + 4063232);
  u16* wt2r_h = (u16*)(ws + 4194304);
  u16* wt2r_l = (u16*)(ws + 4325376);
  char* big = ws + 4718592;
  u16* xf = (u16*)(big);                 // fused x
  u16* n1f = (u16*)(big + SZ_F128);      // fused neigh1
  float* h2 = (float*)(big);             // overlays xf/n1f (disjoint lifetime)
  char* big2 = big + 2 * SZ_F128;
  u16* h1f = (u16*)(big2);               // fused h1
  u16* n2f = (u16*)(big2 + SZ_F256);     // fused neigh2

  hipMemsetAsync(deg, 0, (size_t)M * sizeof(int), stream);
  hipMemsetAsync(cursor, 0, (size_t)M * sizeof(int), stream);

  const int eb = (nE + 255) / 256;
  k_hist<<<eb, 256, 0, stream>>>(dst, deg, nE);
  const int nchunk = (M + 1023) / 1024;
  k_scan_chunks<<<nchunk, 256, 0, stream>>>(deg, rowstart, partials, M);
  k_scan_partials<<<1, 64, 0, stream>>>(partials, nchunk);
  k_add_offsets<<<(M + 1 + 255) / 256, 256, 0, stream>>>(rowstart, partials, M, nE);
  k_fill<<<eb, 256, 0, stream>>>(src, dst, rowstart, cursor, csr, nE);

  // converts
  long nx = (long)M * 128;
  k_cvt<<<(int)((nx / 4 + 255) / 256), 256, 0, stream>>>(x, xf, nx);
  k_cvt_wt<<<(128 * 256 + 255) / 256, 256, 0, stream>>>(w1l, wt1l_h, wt1l_l, 128);
  k_cvt_wt<<<(128 * 256 + 255) / 256, 256, 0, stream>>>(w1r, wt1r_h, wt1r_l, 128);
  k_cvt_wt<<<(256 * 256 + 255) / 256, 256, 0, stream>>>(w2l, wt2l_h, wt2l_l, 256);
  k_cvt_wt<<<(256 * 256 + 255) / 256, 256, 0, stream>>>(w2r, wt2r_h, wt2r_l, 256);

  const int ggrid = Mpad / 64;

  // Layer 1
  k_agg128_hl<<<(M * 64 + 255) / 256, 256, 0, stream>>>(x, rowstart, csr, n1f, M);
  k_gemm_mfma<1><<<ggrid, 256, 0, stream>>>(n1f, xf, wt1l_h, wt1l_l, wt1r_h, wt1r_l,
                                            b1l, h1f, nullptr, M, 128);
  // Layer 2
  k_agg256_hl<<<(M * 64 + 255) / 256, 256, 0, stream>>>(h1f, rowstart, csr, n2f, M);
  k_gemm_mfma<0><<<ggrid, 256, 0, stream>>>(n2f, h1f, wt2l_h, wt2l_l, wt2r_h, wt2r_l,
                                            b2l, nullptr, h2, M, 256);
  // Classifier
  k_classifier<<<(M + 15) / 16, 256, 0, stream>>>(h2, wc, bc, outp, M);
}

// Round 9
// 430.537 us; speedup vs baseline: 1.2387x; 1.0267x over previous
//
#include <hip/hip_runtime.h>
#include <hip/hip_bf16.h>

typedef unsigned short u16;
typedef __attribute__((ext_vector_type(8))) short s16x8;
typedef __attribute__((ext_vector_type(8))) unsigned short u16x8;
typedef __attribute__((ext_vector_type(4))) float f32x4;

#define GLOAD16(src, dst)                                                   \
  __builtin_amdgcn_global_load_lds(                                         \
      (const __attribute__((address_space(1))) void*)(src),                 \
      (__attribute__((address_space(3))) void*)(dst), 16, 0, 0)

__device__ inline u16 f2bf(float f) {
  unsigned u = __float_as_uint(f);
  unsigned r = u + 0x7FFFu + ((u >> 16) & 1u);
  return (u16)(r >> 16);
}
__device__ inline float bf2f(u16 h) { return __uint_as_float(((unsigned)h) << 16); }
__device__ inline void split_hl(float f, u16& hi, u16& lo) {
  hi = f2bf(f);
  lo = f2bf(f - bf2f(hi));
}

// ---------------------------------------------------------------------------
// Fused node-feature layout (GEMM A-side operands): row = KT segments of
// 128B; segment kt = 8 chunks of 16B, content chunk c (c<4: hi of dims
// kt*32+c*8..+7; c>=4: lo of same dims) stored at position c ^ (node&7).
// ---------------------------------------------------------------------------

// ---------------------------------------------------------------------------
// CSR build
// ---------------------------------------------------------------------------
__global__ void k_hist(const int* __restrict__ dst, int* __restrict__ deg, int nE) {
  int i = blockIdx.x * blockDim.x + threadIdx.x;
  if (i < nE) atomicAdd(&deg[dst[i]], 1);
}

__global__ void k_scan_chunks(const int* __restrict__ deg, int* __restrict__ excl,
                              int* __restrict__ partials, int n) {
  __shared__ int sd[256];
  const int t = threadIdx.x;
  const int base = blockIdx.x * 1024 + t * 4;
  int v0 = (base + 0 < n) ? deg[base + 0] : 0;
  int v1 = (base + 1 < n) ? deg[base + 1] : 0;
  int v2 = (base + 2 < n) ? deg[base + 2] : 0;
  int v3 = (base + 3 < n) ? deg[base + 3] : 0;
  sd[t] = v0 + v1 + v2 + v3;
  __syncthreads();
  for (int off = 1; off < 256; off <<= 1) {
    int x = 0;
    if (t >= off) x = sd[t - off];
    __syncthreads();
    sd[t] += x;
    __syncthreads();
  }
  int run = (t > 0) ? sd[t - 1] : 0;
  if (base + 0 < n) excl[base + 0] = run;
  run += v0;
  if (base + 1 < n) excl[base + 1] = run;
  run += v1;
  if (base + 2 < n) excl[base + 2] = run;
  run += v2;
  if (base + 3 < n) excl[base + 3] = run;
  if (t == 255) partials[blockIdx.x] = sd[255];
}

__global__ void k_scan_partials(int* __restrict__ partials, int nchunk) {
  const int t = threadIdx.x;
  int orig = (t < nchunk) ? partials[t] : 0;
  int v = orig;
  for (int off = 1; off < 64; off <<= 1) {
    int y = __shfl_up(v, off, 64);
    if (t >= off) v += y;
  }
  if (t < nchunk) partials[t] = v - orig;
}

__global__ void k_add_offsets(int* __restrict__ rowstart, const int* __restrict__ chunk_off,
                              int n, int nE) {
  int i = blockIdx.x * blockDim.x + threadIdx.x;
  if (i < n) rowstart[i] += chunk_off[i >> 10];
  if (i == n) rowstart[n] = nE;
}

__global__ void k_fill(const int* __restrict__ src, const int* __restrict__ dst,
                       const int* __restrict__ rowstart, int* __restrict__ cursor,
                       int* __restrict__ csr, int nE) {
  int i = blockIdx.x * blockDim.x + threadIdx.x;
  if (i < nE) {
    int d = dst[i];
    int p = rowstart[d] + atomicAdd(&cursor[d], 1);
    csr[p] = src[i];
  }
}

// ---------------------------------------------------------------------------
// x fp32 -> fused layout (K=128: row = 256 shorts)
// ---------------------------------------------------------------------------
__global__ void k_cvt(const float* __restrict__ X, u16* __restrict__ Xf, long n) {
  long i = (long)(blockIdx.x * blockDim.x + threadIdx.x) * 4;
  if (i >= n) return;
  float4 v = *(const float4*)&X[i];
  u16 h[4], lo[4];
  split_hl(v.x, h[0], lo[0]);
  split_hl(v.y, h[1], lo[1]);
  split_hl(v.z, h[2], lo[2]);
  split_hl(v.w, h[3], lo[3]);
  int node = (int)(i >> 7), f = (int)(i & 127);
  int kt = f >> 5, c = (f >> 3) & 3, off = f & 7;
  size_t base = (size_t)node * 256 + kt * 64;
  size_t ohi = base + ((c ^ (node & 7)) * 8) + off;
  size_t olo = base + (((4 + c) ^ (node & 7)) * 8) + off;
  *(ushort4*)&Xf[ohi] = make_ushort4(h[0], h[1], h[2], h[3]);
  *(ushort4*)&Xf[olo] = make_ushort4(lo[0], lo[1], lo[2], lo[3]);
}

// W[K][256] -> packed-swizzled [kt][256 cols][32], col-plane stride 8192 shorts
__global__ void k_cvt_wt(const float* __restrict__ W, u16* __restrict__ thi,
                         u16* __restrict__ tlo, int K) {
  int i = blockIdx.x * blockDim.x + threadIdx.x;
  if (i >= K * 256) return;
  int k = i >> 8, n = i & 255;
  u16 h, l;
  split_hl(W[i], h, l);
  size_t o = (size_t)(k >> 5) * 8192 + (size_t)n * 32 +
             (size_t)(((((k >> 3) & 3) ^ ((n >> 1) & 3)) << 3) + (k & 7));
  thi[o] = h;
  tlo[o] = l;
}

// ---------------------------------------------------------------------------
// Layer-1 aggregation: gather fp32 x rows, 4x unrolled; write fused n1
// ---------------------------------------------------------------------------
__global__ void k_agg128_hl(const float* __restrict__ X, const int* __restrict__ rs,
                            const int* __restrict__ csr, u16* __restrict__ Of, int M) {
  int wid = (blockIdx.x * blockDim.x + threadIdx.x) >> 6;
  int lane = threadIdx.x & 63;
  if (wid >= M) return;
  int s0 = rs[wid], s1 = rs[wid + 1];
  const size_t fo = (size_t)lane * 2;
  float ax = 0.f, ay = 0.f;
  int e = s0;
  for (; e + 3 < s1; e += 4) {
    int n0 = csr[e], n1 = csr[e + 1], n2 = csr[e + 2], n3 = csr[e + 3];
    float2 v0 = *(const float2*)&X[(size_t)n0 * 128 + fo];
    float2 v1 = *(const float2*)&X[(size_t)n1 * 128 + fo];
    float2 v2 = *(const float2*)&X[(size_t)n2 * 128 + fo];
    float2 v3 = *(const float2*)&X[(size_t)n3 * 128 + fo];
    ax += (v0.x + v1.x) + (v2.x + v3.x);
    ay += (v0.y + v1.y) + (v2.y + v3.y);
  }
  for (; e < s1; ++e) {
    float2 v = *(const float2*)&X[(size_t)csr[e] * 128 + fo];
    ax += v.x;
    ay += v.y;
  }
  float inv = 1.0f / fmaxf((float)(s1 - s0), 1.0f);
  ax *= inv;
  ay *= inv;
  u16 h0, l0, h1, l1;
  split_hl(ax, h0, l0);
  split_hl(ay, h1, l1);
  int kt = lane >> 4, c = (lane >> 2) & 3, off = (2 * lane) & 7;
  size_t base = (size_t)wid * 256 + kt * 64;
  *(ushort2*)&Of[base + ((c ^ (wid & 7)) * 8) + off] = make_ushort2(h0, h1);
  *(ushort2*)&Of[base + (((4 + c) ^ (wid & 7)) * 8) + off] = make_ushort2(l0, l1);
}

// ---------------------------------------------------------------------------
// Layer-2 aggregation: gather fused h1 rows (1KB contiguous per edge),
// 4x unrolled; write fused n2.  Lane l owns chunk c=l&7 of segment kt=l>>3.
// ---------------------------------------------------------------------------
__global__ void k_agg256_hl(const u16* __restrict__ Xf, const int* __restrict__ rs,
                            const int* __restrict__ csr, u16* __restrict__ Of, int M) {
  int wid = (blockIdx.x * blockDim.x + threadIdx.x) >> 6;
  int lane = threadIdx.x & 63;
  if (wid >= M) return;
  int s0 = rs[wid], s1 = rs[wid + 1];
  const int kt = lane >> 3, lc = lane & 7;
  const size_t seg = (size_t)kt * 64;
  float acc[8];
#pragma unroll
  for (int j = 0; j < 8; ++j) acc[j] = 0.f;
  int e = s0;
  for (; e + 3 < s1; e += 4) {
    int n0 = csr[e], n1 = csr[e + 1], n2 = csr[e + 2], n3 = csr[e + 3];
    u16x8 v0 = *(const u16x8*)&Xf[(size_t)n0 * 512 + seg + ((lc ^ (n0 & 7)) * 8)];
    u16x8 v1 = *(const u16x8*)&Xf[(size_t)n1 * 512 + seg + ((lc ^ (n1 & 7)) * 8)];
    u16x8 v2 = *(const u16x8*)&Xf[(size_t)n2 * 512 + seg + ((lc ^ (n2 & 7)) * 8)];
    u16x8 v3 = *(const u16x8*)&Xf[(size_t)n3 * 512 + seg + ((lc ^ (n3 & 7)) * 8)];
#pragma unroll
    for (int j = 0; j < 8; ++j)
      acc[j] += (bf2f(v0[j]) + bf2f(v1[j])) + (bf2f(v2[j]) + bf2f(v3[j]));
  }
  for (; e < s1; ++e) {
    int na = csr[e];
    u16x8 va = *(const u16x8*)&Xf[(size_t)na * 512 + seg + ((lc ^ (na & 7)) * 8)];
#pragma unroll
    for (int j = 0; j < 8; ++j) acc[j] += bf2f(va[j]);
  }
  float inv = 1.0f / fmaxf((float)(s1 - s0), 1.0f);
  u16x8 ov;
  const bool isHi = lc < 4;
#pragma unroll
  for (int j = 0; j < 8; ++j) {
    float tot = (acc[j] + __shfl_xor(acc[j], 4)) * inv;
    u16 h, lo2;
    split_hl(tot, h, lo2);
    ov[j] = isHi ? h : lo2;
  }
  size_t o = (size_t)wid * 512 + seg + ((lc ^ (wid & 7)) * 8);
  *(u16x8*)&Of[o] = ov;
}

// ---------------------------------------------------------------------------
// Dual bf16x3 MFMA GEMM, counted-vmcnt pipeline, fused-A operands:
// C[M][0:256] = relu(A1@W1 + A2@W2 + bias).  BM=64, BN=256, BK=32.
// OUT_HL=1: write fused hi/lo; OUT_HL=0: write plain bf16 [M][256].
// ---------------------------------------------------------------------------
template <int OUT_HL>
__global__ __launch_bounds__(256) void k_gemm_mfma(
    const u16* __restrict__ A1, const u16* __restrict__ A2,
    const u16* __restrict__ W1h, const u16* __restrict__ W1l,
    const u16* __restrict__ W2h, const u16* __restrict__ W2l,
    const float* __restrict__ bias, u16* __restrict__ Ofu,
    u16* __restrict__ Obf, int M, int K) {
  __shared__ short sA[2][4096], sBh[2][8192], sBl[2][8192];
  const int t = threadIdx.x;
  const int l = t & 63;
  const int w = t >> 6;
  const int bm0 = blockIdx.x * 64;
  const int KT = K >> 5;
  const int NT = 2 * KT;
  const int rowS = K * 2;

  f32x4 acc[4][4];
#pragma unroll
  for (int m = 0; m < 4; m++)
#pragma unroll
    for (int n = 0; n < 4; n++) acc[m][n] = (f32x4){0.f, 0.f, 0.f, 0.f};

#define STAGE(buf, it)                                                        \
  do {                                                                        \
    int ph_ = (it) >= KT;                                                     \
    int kt_ = (it) - (ph_ ? KT : 0);                                          \
    const u16* A_ = ph_ ? A2 : A1;                                            \
    const u16* Bh_ = ph_ ? W2h : W1h;                                         \
    const u16* Bl_ = ph_ ? W2l : W1l;                                         \
    size_t a0_ = (size_t)(bm0 + (t >> 3)) * rowS + kt_ * 64 + (t & 7) * 8;    \
    size_t a1_ = (size_t)(bm0 + 32 + (t >> 3)) * rowS + kt_ * 64 + (t & 7) * 8; \
    GLOAD16(A_ + a0_, &sA[buf][t * 8]);                                       \
    GLOAD16(A_ + a1_, &sA[buf][2048 + t * 8]);                                \
    size_t bb_ = (size_t)kt_ * 8192 + t * 8;                                  \
    GLOAD16(Bh_ + bb_ + 0 * 2048, &sBh[buf][t * 8 + 0 * 2048]);               \
    GLOAD16(Bh_ + bb_ + 1 * 2048, &sBh[buf][t * 8 + 1 * 2048]);               \
    GLOAD16(Bh_ + bb_ + 2 * 2048, &sBh[buf][t * 8 + 2 * 2048]);               \
    GLOAD16(Bh_ + bb_ + 3 * 2048, &sBh[buf][t * 8 + 3 * 2048]);               \
    GLOAD16(Bl_ + bb_ + 0 * 2048, &sBl[buf][t * 8 + 0 * 2048]);               \
    GLOAD16(Bl_ + bb_ + 1 * 2048, &sBl[buf][t * 8 + 1 * 2048]);               \
    GLOAD16(Bl_ + bb_ + 2 * 2048, &sBl[buf][t * 8 + 2 * 2048]);               \
    GLOAD16(Bl_ + bb_ + 3 * 2048, &sBl[buf][t * 8 + 3 * 2048]);               \
  } while (0)

  STAGE(0, 0);
  STAGE(1, 1);

  const int lr = l & 15;
  const int cw = l >> 4;
  const int pa_hi = (cw ^ (lr & 7)) * 8;
  const int pa_lo = ((4 + cw) ^ (lr & 7)) * 8;
  const int csx = (cw ^ ((lr >> 1) & 3)) * 8;

  for (int it = 0; it < NT; ++it) {
    const int buf = it & 1;
    if (it + 1 < NT) {
      asm volatile("s_waitcnt vmcnt(10)" ::: "memory");
    } else {
      asm volatile("s_waitcnt vmcnt(0)" ::: "memory");
    }
    __builtin_amdgcn_s_barrier();

    s16x8 ah[4], al[4], bh[4], bl[4];
#pragma unroll
    for (int m = 0; m < 4; ++m) {
      int abase = (m * 16 + lr) * 64;
      ah[m] = *(const s16x8*)&sA[buf][abase + pa_hi];
      al[m] = *(const s16x8*)&sA[buf][abase + pa_lo];
    }
#pragma unroll
    for (int n = 0; n < 4; ++n) {
      int bo = (w * 64 + n * 16 + lr) * 32 + csx;
      bh[n] = *(const s16x8*)&sBh[buf][bo];
      bl[n] = *(const s16x8*)&sBl[buf][bo];
    }
    asm volatile("s_waitcnt lgkmcnt(0)" ::: "memory");
    __builtin_amdgcn_sched_barrier(0);
    __builtin_amdgcn_s_barrier();
    if (it + 2 < NT) STAGE(buf, it + 2);

#pragma unroll
    for (int n = 0; n < 4; ++n) {
#pragma unroll
      for (int m = 0; m < 4; ++m) {
        acc[m][n] = __builtin_amdgcn_mfma_f32_16x16x32_bf16(ah[m], bh[n], acc[m][n], 0, 0, 0);
        acc[m][n] = __builtin_amdgcn_mfma_f32_16x16x32_bf16(al[m], bh[n], acc[m][n], 0, 0, 0);
        acc[m][n] = __builtin_amdgcn_mfma_f32_16x16x32_bf16(ah[m], bl[n], acc[m][n], 0, 0, 0);
      }
    }
  }
#undef STAGE

  const int colb = w * 64 + lr;
  const int rwb = bm0 + (l >> 4) * 4;
#pragma unroll
  for (int n = 0; n < 4; ++n) {
    int col = colb + n * 16;
    float bc = bias[col];
    int ckt = col >> 5, cc = (col >> 3) & 3, coff = col & 7;
#pragma unroll
    for (int m = 0; m < 4; ++m) {
#pragma unroll
      for (int j = 0; j < 4; ++j) {
        int r = rwb + m * 16 + j;
        if (r < M) {
          float v = fmaxf(acc[m][n][j] + bc, 0.f);
          if (OUT_HL) {
            u16 h, lo2;
            split_hl(v, h, lo2);
            size_t base = (size_t)r * 512 + ckt * 64;
            Ofu[base + ((cc ^ (r & 7)) * 8) + coff] = h;
            Ofu[base + (((4 + cc) ^ (r & 7)) * 8) + coff] = lo2;
          } else {
            Obf[(size_t)r * 256 + col] = f2bf(v);
          }
        }
      }
    }
  }
}

// ---------------------------------------------------------------------------
// Classifier: out[M][16] = h2[M][256](bf16) @ wc[256][16] + bc
// ---------------------------------------------------------------------------
__global__ void k_classifier(const u16* __restrict__ h2, const float* __restrict__ wc,
                             const float* __restrict__ bc, float* __restrict__ outv, int M) {
  __shared__ float wcs[4096];
  __shared__ float bcs[16];
  const int t = threadIdx.x;
  for (int i = t; i < 4096; i += 256) wcs[i] = wc[i];
  if (t < 16) bcs[t] = bc[t];
  __syncthreads();
  int row = blockIdx.x * 16 + (t >> 4);
  int cls = t & 15;
  if (row >= M) return;
  const u16* hr = h2 + (size_t)row * 256;
  float acc = 0.f;
  for (int k = 0; k < 256; k += 8) {
    u16x8 h = *(const u16x8*)&hr[k];
#pragma unroll
    for (int j = 0; j < 8; ++j) acc += bf2f(h[j]) * wcs[(k + j) * 16 + cls];
  }
  outv[(size_t)row * 16 + cls] = acc + bcs[cls];
}

// ---------------------------------------------------------------------------
extern "C" void kernel_launch(void* const* d_in, const int* in_sizes, int n_in,
                              void* d_out, int out_size, void* d_ws, size_t ws_size,
                              hipStream_t stream) {
  const float* x = (const float*)d_in[0];
  const int* ei = (const int*)d_in[1];
  const float* w1l = (const float*)d_in[2];
  const float* b1l = (const float*)d_in[3];
  const float* w1r = (const float*)d_in[4];
  const float* w2l = (const float*)d_in[5];
  const float* b2l = (const float*)d_in[6];
  const float* w2r = (const float*)d_in[7];
  const float* wc = (const float*)d_in[8];
  const float* bc = (const float*)d_in[9];
  float* outp = (float*)d_out;

  const int nE = in_sizes[1] / 2;      // 600000
  const int M = in_sizes[0] / 128;     // 50000
  const int Mpad = (M + 63) & ~63;     // 50048
  const int* src = ei;
  const int* dst = ei + nE;

  char* ws = (char*)d_ws;
  const size_t SZ_F128 = (size_t)Mpad * 256 * 2;
  const size_t SZ_F256 = (size_t)Mpad * 512 * 2;

  int* deg = (int*)(ws + 0);
  int* cursor = (int*)(ws + 262144);
  int* rowstart = (int*)(ws + 524288);
  int* partials = (int*)(ws + 786432);
  int* csr = (int*)(ws + 1048576);
  u16* wt1l_h = (u16*)(ws + 3670016);
  u16* wt1l_l = (u16*)(ws + 3735552);
  u16* wt1r_h = (u16*)(ws + 3801088);
  u16* wt1r_l = (u16*)(ws + 3866624);
  u16* wt2l_h = (u16*)(ws + 3932160);
  u16* wt2l_l = (u16*)(ws + 4063232);
  u16* wt2r_h = (u16*)(ws + 4194304);
  u16* wt2r_l = (u16*)(ws + 4325376);
  char* big = ws + 4718592;
  u16* xf = (u16*)(big);                 // fused x
  u16* n1f = (u16*)(big + SZ_F128);      // fused neigh1
  u16* h2b = (u16*)(big);                // bf16 h2, overlays xf/n1f
  char* big2 = big + 2 * SZ_F128;
  u16* h1f = (u16*)(big2);               // fused h1
  u16* n2f = (u16*)(big2 + SZ_F256);     // fused neigh2

  hipMemsetAsync(deg, 0, (size_t)M * sizeof(int), stream);
  hipMemsetAsync(cursor, 0, (size_t)M * sizeof(int), stream);

  const int eb = (nE + 255) / 256;
  k_hist<<<eb, 256, 0, stream>>>(dst, deg, nE);
  const int nchunk = (M + 1023) / 1024;
  k_scan_chunks<<<nchunk, 256, 0, stream>>>(deg, rowstart, partials, M);
  k_scan_partials<<<1, 64, 0, stream>>>(partials, nchunk);
  k_add_offsets<<<(M + 1 + 255) / 256, 256, 0, stream>>>(rowstart, partials, M, nE);
  k_fill<<<eb, 256, 0, stream>>>(src, dst, rowstart, cursor, csr, nE);

  // converts
  long nx = (long)M * 128;
  k_cvt<<<(int)((nx / 4 + 255) / 256), 256, 0, stream>>>(x, xf, nx);
  k_cvt_wt<<<(128 * 256 + 255) / 256, 256, 0, stream>>>(w1l, wt1l_h, wt1l_l, 128);
  k_cvt_wt<<<(128 * 256 + 255) / 256, 256, 0, stream>>>(w1r, wt1r_h, wt1r_l, 128);
  k_cvt_wt<<<(256 * 256 + 255) / 256, 256, 0, stream>>>(w2l, wt2l_h, wt2l_l, 256);
  k_cvt_wt<<<(256 * 256 + 255) / 256, 256, 0, stream>>>(w2r, wt2r_h, wt2r_l, 256);

  const int ggrid = Mpad / 64;

  // Layer 1
  k_agg128_hl<<<(M * 64 + 255) / 256, 256, 0, stream>>>(x, rowstart, csr, n1f, M);
  k_gemm_mfma<1><<<ggrid, 256, 0, stream>>>(n1f, xf, wt1l_h, wt1l_l, wt1r_h, wt1r_l,
                                            b1l, h1f, nullptr, M, 128);
  // Layer 2
  k_agg256_hl<<<(M * 64 + 255) / 256, 256, 0, stream>>>(h1f, rowstart, csr, n2f, M);
  k_gemm_mfma<0><<<ggrid, 256, 0, stream>>>(n2f, h1f, wt2l_h, wt2l_l, wt2r_h, wt2r_l,
                                            b2l, nullptr, h2b, M, 256);
  // Classifier
  k_classifier<<<(M + 15) / 16, 256, 0, stream>>>(h2b, wc, bc, outp, M);
}

// Round 10
// 419.172 us; speedup vs baseline: 1.2723x; 1.0271x over previous
//
#include <hip/hip_runtime.h>
#include <hip/hip_bf16.h>

typedef unsigned short u16;
typedef __attribute__((ext_vector_type(8))) short s16x8;
typedef __attribute__((ext_vector_type(8))) unsigned short u16x8;
typedef __attribute__((ext_vector_type(4))) float f32x4;

#define GLOAD16(src, dst)                                                   \
  __builtin_amdgcn_global_load_lds(                                         \
      (const __attribute__((address_space(1))) void*)(src),                 \
      (__attribute__((address_space(3))) void*)(dst), 16, 0, 0)

__device__ inline u16 f2bf(float f) {
  unsigned u = __float_as_uint(f);
  unsigned r = u + 0x7FFFu + ((u >> 16) & 1u);
  return (u16)(r >> 16);
}
__device__ inline float bf2f(u16 h) { return __uint_as_float(((unsigned)h) << 16); }
__device__ inline void split_hl(float f, u16& hi, u16& lo) {
  hi = f2bf(f);
  lo = f2bf(f - bf2f(hi));
}

// ---------------------------------------------------------------------------
// Fused node-feature layout (GEMM A-side operands): row = KT segments of
// 128B; segment kt = 8 chunks of 16B, content chunk c (c<4: hi of dims
// kt*32+c*8..+7; c>=4: lo of same dims) stored at position c ^ (node&7).
// Note: for c<4, positions {c^(n&7)} occupy ONE aligned 64B half of the
// segment -> hi-only gathers read full cache lines.
// ---------------------------------------------------------------------------

// ---------------------------------------------------------------------------
// CSR build
// ---------------------------------------------------------------------------
__global__ void k_hist(const int* __restrict__ dst, int* __restrict__ deg, int nE) {
  int i = blockIdx.x * blockDim.x + threadIdx.x;
  if (i < nE) atomicAdd(&deg[dst[i]], 1);
}

__global__ void k_scan_chunks(const int* __restrict__ deg, int* __restrict__ excl,
                              int* __restrict__ partials, int n) {
  __shared__ int sd[256];
  const int t = threadIdx.x;
  const int base = blockIdx.x * 1024 + t * 4;
  int v0 = (base + 0 < n) ? deg[base + 0] : 0;
  int v1 = (base + 1 < n) ? deg[base + 1] : 0;
  int v2 = (base + 2 < n) ? deg[base + 2] : 0;
  int v3 = (base + 3 < n) ? deg[base + 3] : 0;
  sd[t] = v0 + v1 + v2 + v3;
  __syncthreads();
  for (int off = 1; off < 256; off <<= 1) {
    int x = 0;
    if (t >= off) x = sd[t - off];
    __syncthreads();
    sd[t] += x;
    __syncthreads();
  }
  int run = (t > 0) ? sd[t - 1] : 0;
  if (base + 0 < n) excl[base + 0] = run;
  run += v0;
  if (base + 1 < n) excl[base + 1] = run;
  run += v1;
  if (base + 2 < n) excl[base + 2] = run;
  run += v2;
  if (base + 3 < n) excl[base + 3] = run;
  if (t == 255) partials[blockIdx.x] = sd[255];
}

__global__ void k_scan_partials(int* __restrict__ partials, int nchunk) {
  const int t = threadIdx.x;
  int orig = (t < nchunk) ? partials[t] : 0;
  int v = orig;
  for (int off = 1; off < 64; off <<= 1) {
    int y = __shfl_up(v, off, 64);
    if (t >= off) v += y;
  }
  if (t < nchunk) partials[t] = v - orig;
}

__global__ void k_add_offsets(int* __restrict__ rowstart, const int* __restrict__ chunk_off,
                              int n, int nE) {
  int i = blockIdx.x * blockDim.x + threadIdx.x;
  if (i < n) rowstart[i] += chunk_off[i >> 10];
  if (i == n) rowstart[n] = nE;
}

__global__ void k_fill(const int* __restrict__ src, const int* __restrict__ dst,
                       const int* __restrict__ rowstart, int* __restrict__ cursor,
                       int* __restrict__ csr, int nE) {
  int i = blockIdx.x * blockDim.x + threadIdx.x;
  if (i < nE) {
    int d = dst[i];
    int p = rowstart[d] + atomicAdd(&cursor[d], 1);
    csr[p] = src[i];
  }
}

// ---------------------------------------------------------------------------
// x fp32 -> fused layout (K=128: row = 256 shorts)
// ---------------------------------------------------------------------------
__global__ void k_cvt(const float* __restrict__ X, u16* __restrict__ Xf, long n) {
  long i = (long)(blockIdx.x * blockDim.x + threadIdx.x) * 4;
  if (i >= n) return;
  float4 v = *(const float4*)&X[i];
  u16 h[4], lo[4];
  split_hl(v.x, h[0], lo[0]);
  split_hl(v.y, h[1], lo[1]);
  split_hl(v.z, h[2], lo[2]);
  split_hl(v.w, h[3], lo[3]);
  int node = (int)(i >> 7), f = (int)(i & 127);
  int kt = f >> 5, c = (f >> 3) & 3, off = f & 7;
  size_t base = (size_t)node * 256 + kt * 64;
  size_t ohi = base + ((c ^ (node & 7)) * 8) + off;
  size_t olo = base + (((4 + c) ^ (node & 7)) * 8) + off;
  *(ushort4*)&Xf[ohi] = make_ushort4(h[0], h[1], h[2], h[3]);
  *(ushort4*)&Xf[olo] = make_ushort4(lo[0], lo[1], lo[2], lo[3]);
}

// W[K][256] -> packed-swizzled [kt][256 cols][32], col-plane stride 8192 shorts
__global__ void k_cvt_wt(const float* __restrict__ W, u16* __restrict__ thi,
                         u16* __restrict__ tlo, int K) {
  int i = blockIdx.x * blockDim.x + threadIdx.x;
  if (i >= K * 256) return;
  int k = i >> 8, n = i & 255;
  u16 h, l;
  split_hl(W[i], h, l);
  size_t o = (size_t)(k >> 5) * 8192 + (size_t)n * 32 +
             (size_t)(((((k >> 3) & 3) ^ ((n >> 1) & 3)) << 3) + (k & 7));
  thi[o] = h;
  tlo[o] = l;
}

// ---------------------------------------------------------------------------
// Layer-1 aggregation: gather HI chunks of fused x rows (256B/edge, full
// 64B lines), mean in fp32, write fused n1.  Lane l: seg kt=l>>4, content
// chunk c=(l&15)>>2, quarter q=l&3 (2 dims).
// ---------------------------------------------------------------------------
__global__ void k_agg128_hl(const u16* __restrict__ Xf, const int* __restrict__ rs,
                            const int* __restrict__ csr, u16* __restrict__ Of, int M) {
  int wid = (blockIdx.x * blockDim.x + threadIdx.x) >> 6;
  int lane = threadIdx.x & 63;
  if (wid >= M) return;
  int s0 = rs[wid], s1 = rs[wid + 1];
  const int kt = lane >> 4, c = (lane >> 2) & 3, q = lane & 3;
  const size_t seg = (size_t)kt * 64 + q * 2;
  float a0 = 0.f, a1 = 0.f;
  int e = s0;
  for (; e + 3 < s1; e += 4) {
    int n0 = csr[e], n1 = csr[e + 1], n2 = csr[e + 2], n3 = csr[e + 3];
    ushort2 v0 = *(const ushort2*)&Xf[(size_t)n0 * 256 + seg + ((c ^ (n0 & 7)) * 8)];
    ushort2 v1 = *(const ushort2*)&Xf[(size_t)n1 * 256 + seg + ((c ^ (n1 & 7)) * 8)];
    ushort2 v2 = *(const ushort2*)&Xf[(size_t)n2 * 256 + seg + ((c ^ (n2 & 7)) * 8)];
    ushort2 v3 = *(const ushort2*)&Xf[(size_t)n3 * 256 + seg + ((c ^ (n3 & 7)) * 8)];
    a0 += (bf2f(v0.x) + bf2f(v1.x)) + (bf2f(v2.x) + bf2f(v3.x));
    a1 += (bf2f(v0.y) + bf2f(v1.y)) + (bf2f(v2.y) + bf2f(v3.y));
  }
  for (; e < s1; ++e) {
    int na = csr[e];
    ushort2 v = *(const ushort2*)&Xf[(size_t)na * 256 + seg + ((c ^ (na & 7)) * 8)];
    a0 += bf2f(v.x);
    a1 += bf2f(v.y);
  }
  float inv = 1.0f / fmaxf((float)(s1 - s0), 1.0f);
  a0 *= inv;
  a1 *= inv;
  u16 h0, l0, h1, l1;
  split_hl(a0, h0, l0);
  split_hl(a1, h1, l1);
  const int u = wid & 7;
  size_t base = (size_t)wid * 256 + kt * 64 + q * 2;
  *(ushort2*)&Of[base + ((c ^ u) * 8)] = make_ushort2(h0, h1);
  *(ushort2*)&Of[base + (((4 + c) ^ u) * 8)] = make_ushort2(l0, l1);
}

// ---------------------------------------------------------------------------
// Layer-2 aggregation: gather HI chunks of fused h1 rows (512B/edge, full
// 64B lines), mean in fp32, write fused n2.  Lane l: seg kt=l>>3, content
// chunk c=(l&7)>>1, half h=l&1 (4 dims).
// ---------------------------------------------------------------------------
__global__ void k_agg256_hl(const u16* __restrict__ Xf, const int* __restrict__ rs,
                            const int* __restrict__ csr, u16* __restrict__ Of, int M) {
  int wid = (blockIdx.x * blockDim.x + threadIdx.x) >> 6;
  int lane = threadIdx.x & 63;
  if (wid >= M) return;
  int s0 = rs[wid], s1 = rs[wid + 1];
  const int kt = lane >> 3, c = (lane >> 1) & 3, h = lane & 1;
  const size_t seg = (size_t)kt * 64 + h * 4;
  float a0 = 0.f, a1 = 0.f, a2 = 0.f, a3 = 0.f;
  int e = s0;
  for (; e + 3 < s1; e += 4) {
    int n0 = csr[e], n1 = csr[e + 1], n2 = csr[e + 2], n3 = csr[e + 3];
    ushort4 v0 = *(const ushort4*)&Xf[(size_t)n0 * 512 + seg + ((c ^ (n0 & 7)) * 8)];
    ushort4 v1 = *(const ushort4*)&Xf[(size_t)n1 * 512 + seg + ((c ^ (n1 & 7)) * 8)];
    ushort4 v2 = *(const ushort4*)&Xf[(size_t)n2 * 512 + seg + ((c ^ (n2 & 7)) * 8)];
    ushort4 v3 = *(const ushort4*)&Xf[(size_t)n3 * 512 + seg + ((c ^ (n3 & 7)) * 8)];
    a0 += (bf2f(v0.x) + bf2f(v1.x)) + (bf2f(v2.x) + bf2f(v3.x));
    a1 += (bf2f(v0.y) + bf2f(v1.y)) + (bf2f(v2.y) + bf2f(v3.y));
    a2 += (bf2f(v0.z) + bf2f(v1.z)) + (bf2f(v2.z) + bf2f(v3.z));
    a3 += (bf2f(v0.w) + bf2f(v1.w)) + (bf2f(v2.w) + bf2f(v3.w));
  }
  for (; e < s1; ++e) {
    int na = csr[e];
    ushort4 v = *(const ushort4*)&Xf[(size_t)na * 512 + seg + ((c ^ (na & 7)) * 8)];
    a0 += bf2f(v.x);
    a1 += bf2f(v.y);
    a2 += bf2f(v.z);
    a3 += bf2f(v.w);
  }
  float inv = 1.0f / fmaxf((float)(s1 - s0), 1.0f);
  a0 *= inv;
  a1 *= inv;
  a2 *= inv;
  a3 *= inv;
  u16 h0, l0, h1, l1, h2, l2, h3, l3;
  split_hl(a0, h0, l0);
  split_hl(a1, h1, l1);
  split_hl(a2, h2, l2);
  split_hl(a3, h3, l3);
  const int u = wid & 7;
  size_t base = (size_t)wid * 512 + kt * 64 + h * 4;
  *(ushort4*)&Of[base + ((c ^ u) * 8)] = make_ushort4(h0, h1, h2, h3);
  *(ushort4*)&Of[base + (((4 + c) ^ u) * 8)] = make_ushort4(l0, l1, l2, l3);
}

// ---------------------------------------------------------------------------
// Dual bf16x3 MFMA GEMM, counted-vmcnt pipeline, fused-A operands:
// C[M][0:256] = relu(A1@W1 + A2@W2 + bias).  BM=64, BN=256, BK=32.
// OUT_HL=1: write fused hi/lo; OUT_HL=0: write plain bf16 [M][256].
// ---------------------------------------------------------------------------
template <int OUT_HL>
__global__ __launch_bounds__(256) void k_gemm_mfma(
    const u16* __restrict__ A1, const u16* __restrict__ A2,
    const u16* __restrict__ W1h, const u16* __restrict__ W1l,
    const u16* __restrict__ W2h, const u16* __restrict__ W2l,
    const float* __restrict__ bias, u16* __restrict__ Ofu,
    u16* __restrict__ Obf, int M, int K) {
  __shared__ short sA[2][4096], sBh[2][8192], sBl[2][8192];
  const int t = threadIdx.x;
  const int l = t & 63;
  const int w = t >> 6;
  const int bm0 = blockIdx.x * 64;
  const int KT = K >> 5;
  const int NT = 2 * KT;
  const int rowS = K * 2;

  f32x4 acc[4][4];
#pragma unroll
  for (int m = 0; m < 4; m++)
#pragma unroll
    for (int n = 0; n < 4; n++) acc[m][n] = (f32x4){0.f, 0.f, 0.f, 0.f};

#define STAGE(buf, it)                                                        \
  do {                                                                        \
    int ph_ = (it) >= KT;                                                     \
    int kt_ = (it) - (ph_ ? KT : 0);                                          \
    const u16* A_ = ph_ ? A2 : A1;                                            \
    const u16* Bh_ = ph_ ? W2h : W1h;                                         \
    const u16* Bl_ = ph_ ? W2l : W1l;                                         \
    size_t a0_ = (size_t)(bm0 + (t >> 3)) * rowS + kt_ * 64 + (t & 7) * 8;    \
    size_t a1_ = (size_t)(bm0 + 32 + (t >> 3)) * rowS + kt_ * 64 + (t & 7) * 8; \
    GLOAD16(A_ + a0_, &sA[buf][t * 8]);                                       \
    GLOAD16(A_ + a1_, &sA[buf][2048 + t * 8]);                                \
    size_t bb_ = (size_t)kt_ * 8192 + t * 8;                                  \
    GLOAD16(Bh_ + bb_ + 0 * 2048, &sBh[buf][t * 8 + 0 * 2048]);               \
    GLOAD16(Bh_ + bb_ + 1 * 2048, &sBh[buf][t * 8 + 1 * 2048]);               \
    GLOAD16(Bh_ + bb_ + 2 * 2048, &sBh[buf][t * 8 + 2 * 2048]);               \
    GLOAD16(Bh_ + bb_ + 3 * 2048, &sBh[buf][t * 8 + 3 * 2048]);               \
    GLOAD16(Bl_ + bb_ + 0 * 2048, &sBl[buf][t * 8 + 0 * 2048]);               \
    GLOAD16(Bl_ + bb_ + 1 * 2048, &sBl[buf][t * 8 + 1 * 2048]);               \
    GLOAD16(Bl_ + bb_ + 2 * 2048, &sBl[buf][t * 8 + 2 * 2048]);               \
    GLOAD16(Bl_ + bb_ + 3 * 2048, &sBl[buf][t * 8 + 3 * 2048]);               \
  } while (0)

  STAGE(0, 0);
  STAGE(1, 1);

  const int lr = l & 15;
  const int cw = l >> 4;
  const int pa_hi = (cw ^ (lr & 7)) * 8;
  const int pa_lo = ((4 + cw) ^ (lr & 7)) * 8;
  const int csx = (cw ^ ((lr >> 1) & 3)) * 8;

  for (int it = 0; it < NT; ++it) {
    const int buf = it & 1;
    if (it + 1 < NT) {
      asm volatile("s_waitcnt vmcnt(10)" ::: "memory");
    } else {
      asm volatile("s_waitcnt vmcnt(0)" ::: "memory");
    }
    __builtin_amdgcn_s_barrier();

    s16x8 ah[4], al[4], bh[4], bl[4];
#pragma unroll
    for (int m = 0; m < 4; ++m) {
      int abase = (m * 16 + lr) * 64;
      ah[m] = *(const s16x8*)&sA[buf][abase + pa_hi];
      al[m] = *(const s16x8*)&sA[buf][abase + pa_lo];
    }
#pragma unroll
    for (int n = 0; n < 4; ++n) {
      int bo = (w * 64 + n * 16 + lr) * 32 + csx;
      bh[n] = *(const s16x8*)&sBh[buf][bo];
      bl[n] = *(const s16x8*)&sBl[buf][bo];
    }
    asm volatile("s_waitcnt lgkmcnt(0)" ::: "memory");
    __builtin_amdgcn_sched_barrier(0);
    __builtin_amdgcn_s_barrier();
    if (it + 2 < NT) STAGE(buf, it + 2);

#pragma unroll
    for (int n = 0; n < 4; ++n) {
#pragma unroll
      for (int m = 0; m < 4; ++m) {
        acc[m][n] = __builtin_amdgcn_mfma_f32_16x16x32_bf16(ah[m], bh[n], acc[m][n], 0, 0, 0);
        acc[m][n] = __builtin_amdgcn_mfma_f32_16x16x32_bf16(al[m], bh[n], acc[m][n], 0, 0, 0);
        acc[m][n] = __builtin_amdgcn_mfma_f32_16x16x32_bf16(ah[m], bl[n], acc[m][n], 0, 0, 0);
      }
    }
  }
#undef STAGE

  const int colb = w * 64 + lr;
  const int rwb = bm0 + (l >> 4) * 4;
#pragma unroll
  for (int n = 0; n < 4; ++n) {
    int col = colb + n * 16;
    float bc = bias[col];
    int ckt = col >> 5, cc = (col >> 3) & 3, coff = col & 7;
#pragma unroll
    for (int m = 0; m < 4; ++m) {
#pragma unroll
      for (int j = 0; j < 4; ++j) {
        int r = rwb + m * 16 + j;
        if (r < M) {
          float v = fmaxf(acc[m][n][j] + bc, 0.f);
          if (OUT_HL) {
            u16 h, lo2;
            split_hl(v, h, lo2);
            size_t base = (size_t)r * 512 + ckt * 64;
            Ofu[base + ((cc ^ (r & 7)) * 8) + coff] = h;
            Ofu[base + (((4 + cc) ^ (r & 7)) * 8) + coff] = lo2;
          } else {
            Obf[(size_t)r * 256 + col] = f2bf(v);
          }
        }
      }
    }
  }
}

// ---------------------------------------------------------------------------
// Classifier: out[M][16] = h2[M][256](bf16) @ wc[256][16] + bc
// ---------------------------------------------------------------------------
__global__ void k_classifier(const u16* __restrict__ h2, const float* __restrict__ wc,
                             const float* __restrict__ bc, float* __restrict__ outv, int M) {
  __shared__ float wcs[4096];
  __shared__ float bcs[16];
  const int t = threadIdx.x;
  for (int i = t; i < 4096; i += 256) wcs[i] = wc[i];
  if (t < 16) bcs[t] = bc[t];
  __syncthreads();
  int row = blockIdx.x * 16 + (t >> 4);
  int cls = t & 15;
  if (row >= M) return;
  const u16* hr = h2 + (size_t)row * 256;
  float acc = 0.f;
  for (int k = 0; k < 256; k += 8) {
    u16x8 h = *(const u16x8*)&hr[k];
#pragma unroll
    for (int j = 0; j < 8; ++j) acc += bf2f(h[j]) * wcs[(k + j) * 16 + cls];
  }
  outv[(size_t)row * 16 + cls] = acc + bcs[cls];
}

// ---------------------------------------------------------------------------
extern "C" void kernel_launch(void* const* d_in, const int* in_sizes, int n_in,
                              void* d_out, int out_size, void* d_ws, size_t ws_size,
                              hipStream_t stream) {
  const float* x = (const float*)d_in[0];
  const int* ei = (const int*)d_in[1];
  const float* w1l = (const float*)d_in[2];
  const float* b1l = (const float*)d_in[3];
  const float* w1r = (const float*)d_in[4];
  const float* w2l = (const float*)d_in[5];
  const float* b2l = (const float*)d_in[6];
  const float* w2r = (const float*)d_in[7];
  const float* wc = (const float*)d_in[8];
  const float* bc = (const float*)d_in[9];
  float* outp = (float*)d_out;

  const int nE = in_sizes[1] / 2;      // 600000
  const int M = in_sizes[0] / 128;     // 50000
  const int Mpad = (M + 63) & ~63;     // 50048
  const int* src = ei;
  const int* dst = ei + nE;

  char* ws = (char*)d_ws;
  const size_t SZ_F128 = (size_t)Mpad * 256 * 2;
  const size_t SZ_F256 = (size_t)Mpad * 512 * 2;

  int* deg = (int*)(ws + 0);
  int* cursor = (int*)(ws + 262144);
  int* rowstart = (int*)(ws + 524288);
  int* partials = (int*)(ws + 786432);
  int* csr = (int*)(ws + 1048576);
  u16* wt1l_h = (u16*)(ws + 3670016);
  u16* wt1l_l = (u16*)(ws + 3735552);
  u16* wt1r_h = (u16*)(ws + 3801088);
  u16* wt1r_l = (u16*)(ws + 3866624);
  u16* wt2l_h = (u16*)(ws + 3932160);
  u16* wt2l_l = (u16*)(ws + 4063232);
  u16* wt2r_h = (u16*)(ws + 4194304);
  u16* wt2r_l = (u16*)(ws + 4325376);
  char* big = ws + 4718592;
  u16* xf = (u16*)(big);                 // fused x
  u16* n1f = (u16*)(big + SZ_F128);      // fused neigh1
  u16* h2b = (u16*)(big);                // bf16 h2, overlays xf/n1f
  char* big2 = big + 2 * SZ_F128;
  u16* h1f = (u16*)(big2);               // fused h1
  u16* n2f = (u16*)(big2 + SZ_F256);     // fused neigh2

  hipMemsetAsync(deg, 0, (size_t)M * sizeof(int), stream);
  hipMemsetAsync(cursor, 0, (size_t)M * sizeof(int), stream);

  const int eb = (nE + 255) / 256;
  k_hist<<<eb, 256, 0, stream>>>(dst, deg, nE);
  const int nchunk = (M + 1023) / 1024;
  k_scan_chunks<<<nchunk, 256, 0, stream>>>(deg, rowstart, partials, M);
  k_scan_partials<<<1, 64, 0, stream>>>(partials, nchunk);
  k_add_offsets<<<(M + 1 + 255) / 256, 256, 0, stream>>>(rowstart, partials, M, nE);
  k_fill<<<eb, 256, 0, stream>>>(src, dst, rowstart, cursor, csr, nE);

  // converts
  long nx = (long)M * 128;
  k_cvt<<<(int)((nx / 4 + 255) / 256), 256, 0, stream>>>(x, xf, nx);
  k_cvt_wt<<<(128 * 256 + 255) / 256, 256, 0, stream>>>(w1l, wt1l_h, wt1l_l, 128);
  k_cvt_wt<<<(128 * 256 + 255) / 256, 256, 0, stream>>>(w1r, wt1r_h, wt1r_l, 128);
  k_cvt_wt<<<(256 * 256 + 255) / 256, 256, 0, stream>>>(w2l, wt2l_h, wt2l_l, 256);
  k_cvt_wt<<<(256 * 256 + 255) / 256, 256, 0, stream>>>(w2r, wt2r_h, wt2r_l, 256);

  const int ggrid = Mpad / 64;

  // Layer 1 (agg reads hi chunks of xf)
  k_agg128_hl<<<(M * 64 + 255) / 256, 256, 0, stream>>>(xf, rowstart, csr, n1f, M);
  k_gemm_mfma<1><<<ggrid, 256, 0, stream>>>(n1f, xf, wt1l_h, wt1l_l, wt1r_h, wt1r_l,
                                            b1l, h1f, nullptr, M, 128);
  // Layer 2 (agg reads hi chunks of h1f)
  k_agg256_hl<<<(M * 64 + 255) / 256, 256, 0, stream>>>(h1f, rowstart, csr, n2f, M);
  k_gemm_mfma<0><<<ggrid, 256, 0, stream>>>(n2f, h1f, wt2l_h, wt2l_l, wt2r_h, wt2r_l,
                                            b2l, nullptr, h2b, M, 256);
  // Classifier
  k_classifier<<<(M + 15) / 16, 256, 0, stream>>>(h2b, wc, bc, outp, M);
}